// Round 10
// baseline (65.126 us; speedup 1.0000x reference)
//
#include <hip/hip_runtime.h>

typedef __attribute__((ext_vector_type(4))) float f32x4;
typedef __attribute__((ext_vector_type(8))) short bf16x8;
typedef _Float16 f16x8 __attribute__((ext_vector_type(8)));

#define MFMA16(a, b, c) __builtin_amdgcn_mfma_f32_16x16x32_f16((a), (b), (c), 0, 0, 0)
#define MFMABF(a, b, c) __builtin_amdgcn_mfma_f32_16x16x32_bf16((a), (b), (c), 0, 0, 0)

constexpr size_t TILE_FRAG_BYTES = 8192;               // 64x64 fp16, frag-major
constexpr size_t NTILES = 512;                         // B*H*16
constexpr size_t ARR_S  = NTILES * TILE_FRAG_BYTES;    // 4 MiB (K or V array)
constexpr size_t WS_NEED = 2 * ARR_S;                  // Kfrag + Vfrag

// Swizzled byte offset inside a 64-row x 64-col 2-byte-elem LDS tile/strip.
__device__ __forceinline__ int swz_off(int row, int col) {
    return (row * 128 + col * 2) ^ ((row & 7) << 4);
}
__device__ __forceinline__ f16x8 ld_frag16(const char* tile, int row, int col) {
    return *(const f16x8*)(tile + swz_off(row, col));
}

// ---------------------------------------------------------------------------
// Pre-pass (unchanged, verified): K -> fp16 fragment-major tiles (direct);
// V -> transposed fp16 fragment-major tiles (LDS transpose).
// Frag f=(j*2+kk), lane=g*16+l16:
//   K-frag elem e = K[j*16+l16][kk*32+g*8+e]      (B-frag for QK^T)
//   V-frag elem e = V[kk*32+g*8+e][j*16+l16]      (B-frag for PV, V^T)
// ---------------------------------------------------------------------------
__global__ __launch_bounds__(256) void bigbird_prepass(
    const float* __restrict__ K, const float* __restrict__ V,
    char* __restrict__ ws) {
    __shared__ float vf[64][66];
    const int tile = blockIdx.x;
    const int tid  = threadIdx.x;
    const float* Kt = K + (size_t)tile * 4096;
    const float* Vt = V + (size_t)tile * 4096;
    f16x8* Ko = (f16x8*)(ws + (size_t)tile * TILE_FRAG_BYTES);
    f16x8* Vo = (f16x8*)(ws + ARR_S + (size_t)tile * TILE_FRAG_BYTES);

    {   // V: coalesced load into padded LDS (for transposed gather below)
        const int row = tid >> 2;
        const int c0  = (tid & 3) << 4;
        const float* p = Vt + row * 64 + c0;
        f32x4 e0 = *(const f32x4*)p,       e1 = *(const f32x4*)(p + 4),
              e2 = *(const f32x4*)(p + 8), e3 = *(const f32x4*)(p + 12);
#pragma unroll
        for (int e = 0; e < 4; ++e) {
            vf[row][c0 + e] = e0[e];     vf[row][c0 + 4 + e] = e1[e];
            vf[row][c0 + 8 + e] = e2[e]; vf[row][c0 + 12 + e] = e3[e];
        }
    }
    // K: direct global->convert->frag store (no LDS round trip).
#pragma unroll
    for (int t = 0; t < 2; ++t) {
        int s = tid + t * 256;
        int f = s >> 6, lane = s & 63;
        int j = f >> 1, kk = f & 1;
        int l16 = lane & 15, g = lane >> 4;
        const float* p = Kt + (j * 16 + l16) * 64 + kk * 32 + g * 8;
        f32x4 a = *(const f32x4*)p;
        f32x4 c = *(const f32x4*)(p + 4);
        f16x8 kv;
#pragma unroll
        for (int e = 0; e < 4; ++e) {
            kv[e]     = (_Float16)a[e];
            kv[4 + e] = (_Float16)c[e];
        }
        Ko[s] = kv;
    }
    __syncthreads();
#pragma unroll
    for (int t = 0; t < 2; ++t) {
        int s = tid + t * 256;
        int f = s >> 6, lane = s & 63;
        int j = f >> 1, kk = f & 1;
        int l16 = lane & 15, g = lane >> 4;
        f16x8 vv;
#pragma unroll
        for (int e = 0; e < 8; ++e)
            vv[e] = (_Float16)vf[kk * 32 + g * 8 + e][j * 16 + l16];
        Vo[s] = vv;
    }
}

// ---------------------------------------------------------------------------
// Main: one WG per (b,h,64-row block). WAVE-OWNS-TILES: wave w processes
// tiles i == w (mod 4) over the FULL 64 rows (two-pass fixed-max). Per-wave
// serial chain = 2*(n/4) tile-waits; zero intra-WG VMEM redundancy; no
// in-loop barriers. Exact 4-way (m,l,O) merge at the end via LDS.
// ---------------------------------------------------------------------------
__global__ __launch_bounds__(256) void bigbird_main(
    const float* __restrict__ Q, const float* __restrict__ M,
    const char* __restrict__ ws, float* __restrict__ Out) {
    constexpr int H = 16, F = 1024, D = 64;

    __shared__ char  p_sm[4][8192];     // per-wave 64x64 fp16 P tile
    __shared__ float O_sm[64][65];      // merge buffer (padded)
    __shared__ float m_sm[4][64], l_sm[4][64];
    __shared__ int flags[16];
    __shared__ int list[16];
    __shared__ int ncnt;

    const int bid = blockIdx.x;         // 0..511
    const int bh  = bid >> 4;           // b*16+h
    const int fb  = bid & 15;
    const int b   = bh >> 4;
    const int h   = bh & 15;

    const int tid  = threadIdx.x;
    const int lane = tid & 63;
    const int w    = tid >> 6;          // tile subset 0..3
    const int g    = lane >> 4;
    const int l16  = lane & 15;

    if (tid < 16)
        flags[tid] = (M[((size_t)(h * 1024 + fb * 64)) * 1024 + tid * 64] > 0.5f) ? 1 : 0;

    // Q A-fragments for all 4 row-tiles (fp16, x0.125) straight from global.
    f16x8 qf[4][2];
#pragma unroll
    for (int jr = 0; jr < 4; ++jr) {
        const float* qr = Q + ((size_t)bh * F + fb * 64 + jr * 16 + l16) * D;
#pragma unroll
        for (int kk = 0; kk < 2; ++kk) {
            const float* p = qr + kk * 32 + g * 8;
            f32x4 a = *(const f32x4*)p;
            f32x4 c = *(const f32x4*)(p + 4);
#pragma unroll
            for (int e = 0; e < 8; ++e)
                qf[jr][kk][e] = (_Float16)((e < 4 ? a[e] : c[e - 4]) * 0.125f);
        }
    }
    __syncthreads();
    if (tid == 0) {
        int nn = 0;
        for (int t = 0; t < 16; ++t)
            if (flags[t]) list[nn++] = t;
        ncnt = nn;
    }
    __syncthreads();
    const int n = ncnt;

    const f16x8* Kbase = (const f16x8*)ws + (size_t)bh * 16 * 512;
    const f16x8* Vbase = (const f16x8*)(ws + ARR_S) + (size_t)bh * 16 * 512;
    char* pw = p_sm[w];

    // ---------------- Pass 1: per-row max over this wave's tiles ----------
    float mrow[4][4];                    // [jr][r]
#pragma unroll
    for (int jr = 0; jr < 4; ++jr)
#pragma unroll
        for (int r = 0; r < 4; ++r) mrow[jr][r] = -1e30f;

    for (int i = w; i < n; i += 4) {
        const f16x8* Kf = Kbase + (size_t)list[i] * 512;
        f16x8 kfr[4][2];
#pragma unroll
        for (int jc = 0; jc < 4; ++jc)
#pragma unroll
            for (int kk = 0; kk < 2; ++kk)
                kfr[jc][kk] = Kf[(jc * 2 + kk) * 64 + lane];
#pragma unroll
        for (int jc = 0; jc < 4; ++jc) {
#pragma unroll
            for (int jr = 0; jr < 4; ++jr) {
                f32x4 s = f32x4{0.f, 0.f, 0.f, 0.f};
#pragma unroll
                for (int kk = 0; kk < 2; ++kk)
                    s = MFMA16(qf[jr][kk], kfr[jc][kk], s);
#pragma unroll
                for (int r = 0; r < 4; ++r)
                    mrow[jr][r] = fmaxf(mrow[jr][r], s[r]);
            }
        }
    }
    // One-shot 16-lane reduce (within l16 group).
#pragma unroll
    for (int off = 1; off < 16; off <<= 1)
#pragma unroll
        for (int jr = 0; jr < 4; ++jr)
#pragma unroll
            for (int r = 0; r < 4; ++r)
                mrow[jr][r] = fmaxf(mrow[jr][r], __shfl_xor(mrow[jr][r], off, 64));

    // ---------------- Pass 2: exp(fixed max) + PV over this wave's tiles ---
    f32x4 acc[4][4];                     // [jr][jd]
    float lsum[4][4];                    // [jr][r]
#pragma unroll
    for (int jr = 0; jr < 4; ++jr)
#pragma unroll
        for (int jd = 0; jd < 4; ++jd) acc[jr][jd] = f32x4{0.f, 0.f, 0.f, 0.f};
#pragma unroll
    for (int jr = 0; jr < 4; ++jr)
#pragma unroll
        for (int r = 0; r < 4; ++r) lsum[jr][r] = 0.f;

    for (int i = w; i < n; i += 4) {
        const int tb = list[i];
        const f16x8* Kf = Kbase + (size_t)tb * 512;
        const f16x8* Vf = Vbase + (size_t)tb * 512;
        {
            f16x8 kfr[4][2];
#pragma unroll
            for (int jc = 0; jc < 4; ++jc)
#pragma unroll
                for (int kk = 0; kk < 2; ++kk)
                    kfr[jc][kk] = Kf[(jc * 2 + kk) * 64 + lane];
#pragma unroll
            for (int jc = 0; jc < 4; ++jc) {
#pragma unroll
                for (int jr = 0; jr < 4; ++jr) {
                    f32x4 s = f32x4{0.f, 0.f, 0.f, 0.f};
#pragma unroll
                    for (int kk = 0; kk < 2; ++kk)
                        s = MFMA16(qf[jr][kk], kfr[jc][kk], s);
#pragma unroll
                    for (int r = 0; r < 4; ++r) {
                        float pe = __expf(s[r] - mrow[jr][r]);
                        lsum[jr][r] += pe;
                        *(_Float16*)(pw + swz_off(jr * 16 + g * 4 + r,
                                                  jc * 16 + l16)) = (_Float16)pe;
                    }
                }
            }
        }
        asm volatile("s_waitcnt lgkmcnt(0)" ::: "memory");
        __builtin_amdgcn_sched_barrier(0);
        {
            f16x8 vfr[4][2];
#pragma unroll
            for (int jd = 0; jd < 4; ++jd)
#pragma unroll
                for (int kk = 0; kk < 2; ++kk)
                    vfr[jd][kk] = Vf[(jd * 2 + kk) * 64 + lane];
#pragma unroll
            for (int kk = 0; kk < 2; ++kk)
#pragma unroll
                for (int jr = 0; jr < 4; ++jr) {
                    f16x8 pa = ld_frag16(pw, jr * 16 + l16, kk * 32 + g * 8);
#pragma unroll
                    for (int jd = 0; jd < 4; ++jd)
                        acc[jr][jd] = MFMA16(pa, vfr[jd][kk], acc[jr][jd]);
                }
        }
    }

    // l reduce (within l16 group).
#pragma unroll
    for (int off = 1; off < 16; off <<= 1)
#pragma unroll
        for (int jr = 0; jr < 4; ++jr)
#pragma unroll
            for (int r = 0; r < 4; ++r)
                lsum[jr][r] += __shfl_xor(lsum[jr][r], off, 64);

    // ---------------- 4-way exact merge ------------------------------------
    if (l16 == 0) {
#pragma unroll
        for (int jr = 0; jr < 4; ++jr)
#pragma unroll
            for (int r = 0; r < 4; ++r) {
                int row = jr * 16 + g * 4 + r;
                m_sm[w][row] = mrow[jr][r];
                l_sm[w][row] = lsum[jr][r];
            }
    }
    __syncthreads();
    float wgt[4][4];
#pragma unroll
    for (int jr = 0; jr < 4; ++jr)
#pragma unroll
        for (int r = 0; r < 4; ++r) {
            int row = jr * 16 + g * 4 + r;
            float Mx = fmaxf(fmaxf(m_sm[0][row], m_sm[1][row]),
                             fmaxf(m_sm[2][row], m_sm[3][row]));
            wgt[jr][r] = __expf(mrow[jr][r] - Mx);
        }
    // Sequential accumulate O_sm (exact, 4 barrier rounds).
#pragma unroll
    for (int ww = 0; ww < 4; ++ww) {
        if (w == ww) {
#pragma unroll
            for (int jr = 0; jr < 4; ++jr)
#pragma unroll
                for (int jd = 0; jd < 4; ++jd)
#pragma unroll
                    for (int r = 0; r < 4; ++r) {
                        int row = jr * 16 + g * 4 + r;
                        int col = jd * 16 + l16;
                        float v = acc[jr][jd][r] * wgt[jr][r];
                        if (ww == 0) O_sm[row][col] = v;
                        else         O_sm[row][col] += v;
                    }
        }
        __syncthreads();
    }

    // Epilogue: thread owns (row=tid>>2, 16-col slice q4).
    {
        const int row = tid >> 2;
        const int q4  = tid & 3;
        float Mx = fmaxf(fmaxf(m_sm[0][row], m_sm[1][row]),
                         fmaxf(m_sm[2][row], m_sm[3][row]));
        float L = 0.f;
#pragma unroll
        for (int ww = 0; ww < 4; ++ww)
            L += l_sm[ww][row] * __expf(m_sm[ww][row] - Mx);
        float inv = 1.0f / L;
        int f = fb * 64 + row;
        float* ob = Out + ((size_t)(b * F + f) * H + h) * D + q4 * 16;
#pragma unroll
        for (int e = 0; e < 16; ++e)
            ob[e] = O_sm[row][q4 * 16 + e] * inv;
    }
}

// ---------------------------------------------------------------------------
// Fallback (verified R0-style kernel): used only if ws is too small.
// ---------------------------------------------------------------------------
__device__ __forceinline__ unsigned short f2bf(float x) {
    unsigned u = __builtin_bit_cast(unsigned, x);
    unsigned r = u + 0x7fffu + ((u >> 16) & 1u);
    return (unsigned short)(r >> 16);
}
__device__ __forceinline__ float bf2f(unsigned short h) {
    return __builtin_bit_cast(float, (unsigned)h << 16);
}
__device__ __forceinline__ bf16x8 ld_fragb(const char* tile, int row, int col) {
    return *(const bf16x8*)(tile + swz_off(row, col));
}
__device__ __forceinline__ void stage_rm_fb(const float* __restrict__ src,
                                            char* hi_t, char* lo_t, float scale) {
    const int tid = threadIdx.x;
    const int row = tid >> 2;
    const int c0  = (tid & 3) << 4;
    const float* p = src + row * 64 + c0;
    f32x4 vv[4] = { *(const f32x4*)(p), *(const f32x4*)(p + 4),
                    *(const f32x4*)(p + 8), *(const f32x4*)(p + 12) };
    bf16x8 h2[2], l2[2];
#pragma unroll
    for (int e = 0; e < 16; ++e) {
        float x = vv[e >> 2][e & 3] * scale;
        unsigned short hb = f2bf(x);
        unsigned short lb = f2bf(x - bf2f(hb));
        h2[e >> 3][e & 7] = (short)hb;
        l2[e >> 3][e & 7] = (short)lb;
    }
#pragma unroll
    for (int gi = 0; gi < 2; ++gi) {
        int off = swz_off(row, c0 + gi * 8);
        *(bf16x8*)(hi_t + off) = h2[gi];
        *(bf16x8*)(lo_t + off) = l2[gi];
    }
}
__device__ __forceinline__ void stage_tr_fb(const float* __restrict__ src,
                                            char* hi_t, char* lo_t) {
    const int tid = threadIdx.x;
    const int t  = tid >> 2;
    const int c0 = (tid & 3) << 4;
    const float* p = src + t * 64 + c0;
    f32x4 vv[4] = { *(const f32x4*)(p), *(const f32x4*)(p + 4),
                    *(const f32x4*)(p + 8), *(const f32x4*)(p + 12) };
#pragma unroll
    for (int e = 0; e < 16; ++e) {
        float x = vv[e >> 2][e & 3];
        unsigned short hb = f2bf(x);
        unsigned short lb = f2bf(x - bf2f(hb));
        int d = c0 + e;
        int off = (d * 128 + t * 2) ^ ((d & 7) << 4);
        *(unsigned short*)(hi_t + off) = hb;
        *(unsigned short*)(lo_t + off) = lb;
    }
}
__global__ __launch_bounds__(256) void bigbird_kernel_fb(
    const float* __restrict__ Q, const float* __restrict__ K,
    const float* __restrict__ V, const float* __restrict__ M,
    float* __restrict__ Out) {
    constexpr int H = 16, F = 1024, D = 64;
    __shared__ char kq_hi[8192];
    __shared__ char kq_lo[8192];
    __shared__ char vt_hi[8192];
    __shared__ char vt_lo[8192];
    __shared__ char p_smf[8192];
    __shared__ int flags[16];
    const int bid = blockIdx.x;
    const int fb  = bid & 15;
    const int h   = (bid >> 4) & 15;
    const int b   = bid >> 8;
    const int tid  = threadIdx.x;
    const int lane = tid & 63;
    const int w    = tid >> 6;
    const int g    = lane >> 4;
    const int l16  = lane & 15;
    if (tid < 16)
        flags[tid] = (M[(h * 1024 + fb * 64) * 1024 + tid * 64] > 0.5f) ? 1 : 0;
    const float* qb = Q + ((size_t)(b * H + h) * F + fb * 64) * D;
    stage_rm_fb(qb, kq_hi, kq_lo, 0.125f);
    __syncthreads();
    bf16x8 qh[2], ql[2];
#pragma unroll
    for (int kk = 0; kk < 2; ++kk) {
        qh[kk] = ld_fragb(kq_hi, w * 16 + l16, kk * 32 + g * 8);
        ql[kk] = ld_fragb(kq_lo, w * 16 + l16, kk * 32 + g * 8);
    }
    f32x4 acc[4];
    float m_r[4], l_r[4];
#pragma unroll
    for (int j = 0; j < 4; ++j) acc[j] = f32x4{0.f, 0.f, 0.f, 0.f};
#pragma unroll
    for (int r = 0; r < 4; ++r) { m_r[r] = -1e30f; l_r[r] = 0.f; }
    const float* kb = K + (size_t)(b * H + h) * 1024 * D;
    const float* vb = V + (size_t)(b * H + h) * 1024 * D;
    for (int tb = 0; tb < 16; ++tb) {
        if (!flags[tb]) continue;
        __syncthreads();
        stage_rm_fb(kb + tb * 64 * D, kq_hi, kq_lo, 1.0f);
        stage_tr_fb(vb + tb * 64 * D, vt_hi, vt_lo);
        __syncthreads();
        f32x4 s[4];
#pragma unroll
        for (int j = 0; j < 4; ++j) {
            s[j] = f32x4{0.f, 0.f, 0.f, 0.f};
#pragma unroll
            for (int kk = 0; kk < 2; ++kk) {
                bf16x8 bhf = ld_fragb(kq_hi, j * 16 + l16, kk * 32 + g * 8);
                bf16x8 blf = ld_fragb(kq_lo, j * 16 + l16, kk * 32 + g * 8);
                s[j] = MFMABF(qh[kk], bhf, s[j]);
                s[j] = MFMABF(qh[kk], blf, s[j]);
                s[j] = MFMABF(ql[kk], bhf, s[j]);
            }
        }
        float rmax[4];
#pragma unroll
        for (int r = 0; r < 4; ++r)
            rmax[r] = fmaxf(fmaxf(s[0][r], s[1][r]), fmaxf(s[2][r], s[3][r]));
#pragma unroll
        for (int off = 1; off < 16; off <<= 1)
#pragma unroll
            for (int r = 0; r < 4; ++r)
                rmax[r] = fmaxf(rmax[r], __shfl_xor(rmax[r], off, 64));
        float alpha[4], psum[4];
#pragma unroll
        for (int r = 0; r < 4; ++r) {
            float mn = fmaxf(m_r[r], rmax[r]);
            alpha[r] = __expf(m_r[r] - mn);
            m_r[r]   = mn;
            psum[r]  = 0.f;
        }
#pragma unroll
        for (int j = 0; j < 4; ++j)
#pragma unroll
            for (int r = 0; r < 4; ++r) {
                float pe = __expf(s[j][r] - m_r[r]);
                s[j][r] = pe;
                psum[r] += pe;
            }
#pragma unroll
        for (int off = 1; off < 16; off <<= 1)
#pragma unroll
            for (int r = 0; r < 4; ++r)
                psum[r] += __shfl_xor(psum[r], off, 64);
#pragma unroll
        for (int r = 0; r < 4; ++r)
            l_r[r] = l_r[r] * alpha[r] + psum[r];
#pragma unroll
        for (int j = 0; j < 4; ++j)
#pragma unroll
            for (int r = 0; r < 4; ++r)
                acc[j][r] *= alpha[r];
#pragma unroll
        for (int j = 0; j < 4; ++j)
#pragma unroll
            for (int r = 0; r < 4; ++r) {
                int row = w * 16 + g * 4 + r;
                *(unsigned short*)(p_smf + swz_off(row, j * 16 + l16)) = f2bf(s[j][r]);
            }
        __syncthreads();
#pragma unroll
        for (int kk = 0; kk < 2; ++kk) {
            bf16x8 pa = ld_fragb(p_smf, w * 16 + l16, kk * 32 + g * 8);
#pragma unroll
            for (int jd = 0; jd < 4; ++jd) {
                bf16x8 vh = ld_fragb(vt_hi, jd * 16 + l16, kk * 32 + g * 8);
                bf16x8 vl = ld_fragb(vt_lo, jd * 16 + l16, kk * 32 + g * 8);
                acc[jd] = MFMABF(pa, vh, acc[jd]);
                acc[jd] = MFMABF(pa, vl, acc[jd]);
            }
        }
    }
#pragma unroll
    for (int r = 0; r < 4; ++r) {
        float inv = 1.0f / l_r[r];
        int f = fb * 64 + w * 16 + g * 4 + r;
        float* ob = Out + ((size_t)(b * F + f) * H + h) * D;
#pragma unroll
        for (int jd = 0; jd < 4; ++jd)
            ob[jd * 16 + l16] = acc[jd][r] * inv;
    }
}

extern "C" void kernel_launch(void* const* d_in, const int* in_sizes, int n_in,
                              void* d_out, int out_size, void* d_ws, size_t ws_size,
                              hipStream_t stream) {
    const float* q = (const float*)d_in[0];
    const float* k = (const float*)d_in[1];
    const float* v = (const float*)d_in[2];
    const float* m = (const float*)d_in[3];
    float* out = (float*)d_out;
    if (ws_size >= WS_NEED) {
        bigbird_prepass<<<dim3(512), dim3(256), 0, stream>>>(k, v, (char*)d_ws);
        bigbird_main<<<dim3(512), dim3(256), 0, stream>>>(q, m, (const char*)d_ws, out);
    } else {
        bigbird_kernel_fb<<<dim3(512), dim3(256), 0, stream>>>(q, k, v, m, out);
    }
}

// Round 11
// 43.133 us; speedup vs baseline: 1.5099x; 1.5099x over previous
//
#include <hip/hip_runtime.h>

typedef __attribute__((ext_vector_type(4))) float f32x4;
typedef __attribute__((ext_vector_type(8))) short bf16x8;
typedef _Float16 f16x8 __attribute__((ext_vector_type(8)));

#define MFMA16(a, b, c) __builtin_amdgcn_mfma_f32_16x16x32_f16((a), (b), (c), 0, 0, 0)
#define MFMABF(a, b, c) __builtin_amdgcn_mfma_f32_16x16x32_bf16((a), (b), (c), 0, 0, 0)

constexpr size_t TILE_FRAG_BYTES = 8192;               // 64x64 fp16, frag-major
constexpr size_t NTILES = 512;                         // B*H*16
constexpr size_t ARR_S  = NTILES * TILE_FRAG_BYTES;    // 4 MiB (K or V array)
constexpr size_t WS_NEED = 2 * ARR_S;                  // Kfrag + Vfrag

// Swizzled byte offset inside a 64-row x 64-col 2-byte-elem LDS tile/strip.
__device__ __forceinline__ int swz_off(int row, int col) {
    return (row * 128 + col * 2) ^ ((row & 7) << 4);
}
__device__ __forceinline__ f16x8 ld_frag16(const char* tile, int row, int col) {
    return *(const f16x8*)(tile + swz_off(row, col));
}

// ---------------------------------------------------------------------------
// Pre-pass (unchanged, verified): K -> fp16 fragment-major tiles (direct);
// V -> transposed fp16 fragment-major tiles (LDS transpose).
// Frag f=(j*2+kk), lane=g*16+l16:
//   K-frag elem e = K[j*16+l16][kk*32+g*8+e]      (B-frag for QK^T)
//   V-frag elem e = V[kk*32+g*8+e][j*16+l16]      (B-frag for PV, V^T)
// ---------------------------------------------------------------------------
__global__ __launch_bounds__(256) void bigbird_prepass(
    const float* __restrict__ K, const float* __restrict__ V,
    char* __restrict__ ws) {
    __shared__ float vf[64][66];
    const int tile = blockIdx.x;
    const int tid  = threadIdx.x;
    const float* Kt = K + (size_t)tile * 4096;
    const float* Vt = V + (size_t)tile * 4096;
    f16x8* Ko = (f16x8*)(ws + (size_t)tile * TILE_FRAG_BYTES);
    f16x8* Vo = (f16x8*)(ws + ARR_S + (size_t)tile * TILE_FRAG_BYTES);

    {   // V: coalesced load into padded LDS (for transposed gather below)
        const int row = tid >> 2;
        const int c0  = (tid & 3) << 4;
        const float* p = Vt + row * 64 + c0;
        f32x4 e0 = *(const f32x4*)p,       e1 = *(const f32x4*)(p + 4),
              e2 = *(const f32x4*)(p + 8), e3 = *(const f32x4*)(p + 12);
#pragma unroll
        for (int e = 0; e < 4; ++e) {
            vf[row][c0 + e] = e0[e];     vf[row][c0 + 4 + e] = e1[e];
            vf[row][c0 + 8 + e] = e2[e]; vf[row][c0 + 12 + e] = e3[e];
        }
    }
    // K: direct global->convert->frag store (no LDS round trip).
#pragma unroll
    for (int t = 0; t < 2; ++t) {
        int s = tid + t * 256;
        int f = s >> 6, lane = s & 63;
        int j = f >> 1, kk = f & 1;
        int l16 = lane & 15, g = lane >> 4;
        const float* p = Kt + (j * 16 + l16) * 64 + kk * 32 + g * 8;
        f32x4 a = *(const f32x4*)p;
        f32x4 c = *(const f32x4*)(p + 4);
        f16x8 kv;
#pragma unroll
        for (int e = 0; e < 4; ++e) {
            kv[e]     = (_Float16)a[e];
            kv[4 + e] = (_Float16)c[e];
        }
        Ko[s] = kv;
    }
    __syncthreads();
#pragma unroll
    for (int t = 0; t < 2; ++t) {
        int s = tid + t * 256;
        int f = s >> 6, lane = s & 63;
        int j = f >> 1, kk = f & 1;
        int l16 = lane & 15, g = lane >> 4;
        f16x8 vv;
#pragma unroll
        for (int e = 0; e < 8; ++e)
            vv[e] = (_Float16)vf[kk * 32 + g * 8 + e][j * 16 + l16];
        Vo[s] = vv;
    }
}

// ---------------------------------------------------------------------------
// Main: one WG per (b,h,64-row block); 4 waves = 4 row strips, free-running.
// TWO-PASS fixed-max softmax. NO scheduling fences in the loop: the P-tile
// LDS write/read ordering is tracked by the compiler (plain C++ accesses to
// the same object), so the scheduler is free to hoist tile i+1's global
// fragment loads above tile i's softmax/PV -> cross-iteration pipelining.
// ---------------------------------------------------------------------------
__global__ __launch_bounds__(256) void bigbird_main(
    const float* __restrict__ Q, const float* __restrict__ M,
    const char* __restrict__ ws, float* __restrict__ Out) {
    constexpr int H = 16, F = 1024, D = 64;

    __shared__ char p_sm[4][2048];      // per-wave 16-row P strip
    __shared__ int flags[16];
    __shared__ int list[16];
    __shared__ int ncnt;

    // XCD-grouped remap: all 16 row-blocks of one (b,h) on one XCD.
    const int i0  = blockIdx.x;         // 0..511
    const int xcd = i0 & 7;
    const int q0  = i0 >> 3;            // 0..63
    const int grp = xcd * 4 + (q0 >> 4);// 0..31 == b*16+h
    const int fb  = q0 & 15;            // 64-row block
    const int b   = grp >> 4;
    const int h   = grp & 15;
    const int bh  = grp;

    const int tid  = threadIdx.x;
    const int lane = tid & 63;
    const int w    = tid >> 6;          // row strip 0..3
    const int g    = lane >> 4;
    const int l16  = lane & 15;

    if (tid < 16)
        flags[tid] = (M[((size_t)(h * 1024 + fb * 64)) * 1024 + tid * 64] > 0.5f) ? 1 : 0;

    // Q A-fragments (fp16, x0.125) straight from global.
    f16x8 qf[2];
    {
        const float* qr = Q + ((size_t)bh * F + fb * 64 + w * 16 + l16) * D;
#pragma unroll
        for (int kk = 0; kk < 2; ++kk) {
            const float* p = qr + kk * 32 + g * 8;
            f32x4 a = *(const f32x4*)p;
            f32x4 c = *(const f32x4*)(p + 4);
#pragma unroll
            for (int e = 0; e < 8; ++e)
                qf[kk][e] = (_Float16)((e < 4 ? a[e] : c[e - 4]) * 0.125f);
        }
    }
    __syncthreads();
    if (tid == 0) {
        int nn = 0;
        for (int t = 0; t < 16; ++t)
            if (flags[t]) list[nn++] = t;
        ncnt = nn;
    }
    __syncthreads();
    const int n = ncnt;

    const f16x8* Kbase = (const f16x8*)ws + (size_t)bh * 16 * 512;
    const f16x8* Vbase = (const f16x8*)(ws + ARR_S) + (size_t)bh * 16 * 512;
    char* pw = p_sm[w];

    // ---------------- Pass 1: per-row max (no cross-lane in loop) ----------
    float mrow[4];
#pragma unroll
    for (int r = 0; r < 4; ++r) mrow[r] = -1e30f;

    for (int i = 0; i < n; ++i) {
        const f16x8* Kf = Kbase + (size_t)list[i] * 512;
        f16x8 kfr[4][2];
#pragma unroll
        for (int j = 0; j < 4; ++j)
#pragma unroll
            for (int kk = 0; kk < 2; ++kk)
                kfr[j][kk] = Kf[(j * 2 + kk) * 64 + lane];
        f32x4 sv[4];
#pragma unroll
        for (int j = 0; j < 4; ++j) {
            sv[j] = f32x4{0.f, 0.f, 0.f, 0.f};
#pragma unroll
            for (int kk = 0; kk < 2; ++kk)
                sv[j] = MFMA16(qf[kk], kfr[j][kk], sv[j]);
        }
#pragma unroll
        for (int r = 0; r < 4; ++r)
            mrow[r] = fmaxf(mrow[r],
                      fmaxf(fmaxf(sv[0][r], sv[1][r]), fmaxf(sv[2][r], sv[3][r])));
    }
    // One-shot 16-lane reduce (stays within l16 group).
#pragma unroll
    for (int off = 1; off < 16; off <<= 1)
#pragma unroll
        for (int r = 0; r < 4; ++r)
            mrow[r] = fmaxf(mrow[r], __shfl_xor(mrow[r], off, 64));

    // ---------------- Pass 2: exp with fixed max + PV ----------------------
    f32x4 acc[4];
    float lsum[4];
#pragma unroll
    for (int j = 0; j < 4; ++j) acc[j] = f32x4{0.f, 0.f, 0.f, 0.f};
#pragma unroll
    for (int r = 0; r < 4; ++r) lsum[r] = 0.f;

    for (int i = 0; i < n; ++i) {
        const int tb = list[i];
        const f16x8* Kf = Kbase + (size_t)tb * 512;
        const f16x8* Vf = Vbase + (size_t)tb * 512;
        f16x8 kfr[4][2], vfr[4][2];
#pragma unroll
        for (int j = 0; j < 4; ++j)
#pragma unroll
            for (int kk = 0; kk < 2; ++kk) {
                kfr[j][kk] = Kf[(j * 2 + kk) * 64 + lane];
                vfr[j][kk] = Vf[(j * 2 + kk) * 64 + lane];
            }
        f32x4 sv[4];
#pragma unroll
        for (int j = 0; j < 4; ++j) {
            sv[j] = f32x4{0.f, 0.f, 0.f, 0.f};
#pragma unroll
            for (int kk = 0; kk < 2; ++kk)
                sv[j] = MFMA16(qf[kk], kfr[j][kk], sv[j]);
        }
        // exp against fixed max: fully lane-local, no reduce, no rescale.
#pragma unroll
        for (int j = 0; j < 4; ++j)
#pragma unroll
            for (int r = 0; r < 4; ++r) {
                float pe = __expf(sv[j][r] - mrow[r]);
                sv[j][r] = pe;
                lsum[r] += pe;
            }
        // P (fp16) -> wave-private LDS strip: C-layout -> A-frag reshape.
        // Plain C++ accesses: compiler inserts the precise lgkmcnt ordering
        // and remains free to hoist the NEXT tile's global loads above this.
#pragma unroll
        for (int j = 0; j < 4; ++j)
#pragma unroll
            for (int r = 0; r < 4; ++r)
                *(_Float16*)(pw + swz_off(g * 4 + r, j * 16 + l16)) = (_Float16)sv[j][r];
        // O += P * V
#pragma unroll
        for (int kk = 0; kk < 2; ++kk) {
            f16x8 pa = ld_frag16(pw, l16, kk * 32 + g * 8);
#pragma unroll
            for (int jd = 0; jd < 4; ++jd)
                acc[jd] = MFMA16(pa, vfr[jd][kk], acc[jd]);
        }
    }

    // One-shot l reduce (cols split across the 16-lane group).
#pragma unroll
    for (int off = 1; off < 16; off <<= 1)
#pragma unroll
        for (int r = 0; r < 4; ++r)
            lsum[r] += __shfl_xor(lsum[r], off, 64);

    // Epilogue: normalize, write [B, F, H, D].
#pragma unroll
    for (int r = 0; r < 4; ++r) {
        float inv = 1.0f / lsum[r];
        int f = fb * 64 + w * 16 + g * 4 + r;
        float* ob = Out + ((size_t)(b * F + f) * H + h) * D;
#pragma unroll
        for (int jd = 0; jd < 4; ++jd)
            ob[jd * 16 + l16] = acc[jd][r] * inv;
    }
}

// ---------------------------------------------------------------------------
// Fallback (verified R0-style kernel): used only if ws is too small.
// ---------------------------------------------------------------------------
__device__ __forceinline__ unsigned short f2bf(float x) {
    unsigned u = __builtin_bit_cast(unsigned, x);
    unsigned r = u + 0x7fffu + ((u >> 16) & 1u);
    return (unsigned short)(r >> 16);
}
__device__ __forceinline__ float bf2f(unsigned short h) {
    return __builtin_bit_cast(float, (unsigned)h << 16);
}
__device__ __forceinline__ bf16x8 ld_fragb(const char* tile, int row, int col) {
    return *(const bf16x8*)(tile + swz_off(row, col));
}
__device__ __forceinline__ void stage_rm_fb(const float* __restrict__ src,
                                            char* hi_t, char* lo_t, float scale) {
    const int tid = threadIdx.x;
    const int row = tid >> 2;
    const int c0  = (tid & 3) << 4;
    const float* p = src + row * 64 + c0;
    f32x4 vv[4] = { *(const f32x4*)(p), *(const f32x4*)(p + 4),
                    *(const f32x4*)(p + 8), *(const f32x4*)(p + 12) };
    bf16x8 h2[2], l2[2];
#pragma unroll
    for (int e = 0; e < 16; ++e) {
        float x = vv[e >> 2][e & 3] * scale;
        unsigned short hb = f2bf(x);
        unsigned short lb = f2bf(x - bf2f(hb));
        h2[e >> 3][e & 7] = (short)hb;
        l2[e >> 3][e & 7] = (short)lb;
    }
#pragma unroll
    for (int gi = 0; gi < 2; ++gi) {
        int off = swz_off(row, c0 + gi * 8);
        *(bf16x8*)(hi_t + off) = h2[gi];
        *(bf16x8*)(lo_t + off) = l2[gi];
    }
}
__device__ __forceinline__ void stage_tr_fb(const float* __restrict__ src,
                                            char* hi_t, char* lo_t) {
    const int tid = threadIdx.x;
    const int t  = tid >> 2;
    const int c0 = (tid & 3) << 4;
    const float* p = src + t * 64 + c0;
    f32x4 vv[4] = { *(const f32x4*)(p), *(const f32x4*)(p + 4),
                    *(const f32x4*)(p + 8), *(const f32x4*)(p + 12) };
#pragma unroll
    for (int e = 0; e < 16; ++e) {
        float x = vv[e >> 2][e & 3];
        unsigned short hb = f2bf(x);
        unsigned short lb = f2bf(x - bf2f(hb));
        int d = c0 + e;
        int off = (d * 128 + t * 2) ^ ((d & 7) << 4);
        *(unsigned short*)(hi_t + off) = hb;
        *(unsigned short*)(lo_t + off) = lb;
    }
}
__global__ __launch_bounds__(256) void bigbird_kernel_fb(
    const float* __restrict__ Q, const float* __restrict__ K,
    const float* __restrict__ V, const float* __restrict__ M,
    float* __restrict__ Out) {
    constexpr int H = 16, F = 1024, D = 64;
    __shared__ char kq_hi[8192];
    __shared__ char kq_lo[8192];
    __shared__ char vt_hi[8192];
    __shared__ char vt_lo[8192];
    __shared__ char p_smf[8192];
    __shared__ int flags[16];
    const int bid = blockIdx.x;
    const int fb  = bid & 15;
    const int h   = (bid >> 4) & 15;
    const int b   = bid >> 8;
    const int tid  = threadIdx.x;
    const int lane = tid & 63;
    const int w    = tid >> 6;
    const int g    = lane >> 4;
    const int l16  = lane & 15;
    if (tid < 16)
        flags[tid] = (M[(h * 1024 + fb * 64) * 1024 + tid * 64] > 0.5f) ? 1 : 0;
    const float* qb = Q + ((size_t)(b * H + h) * F + fb * 64) * D;
    stage_rm_fb(qb, kq_hi, kq_lo, 0.125f);
    __syncthreads();
    bf16x8 qh[2], ql[2];
#pragma unroll
    for (int kk = 0; kk < 2; ++kk) {
        qh[kk] = ld_fragb(kq_hi, w * 16 + l16, kk * 32 + g * 8);
        ql[kk] = ld_fragb(kq_lo, w * 16 + l16, kk * 32 + g * 8);
    }
    f32x4 acc[4];
    float m_r[4], l_r[4];
#pragma unroll
    for (int j = 0; j < 4; ++j) acc[j] = f32x4{0.f, 0.f, 0.f, 0.f};
#pragma unroll
    for (int r = 0; r < 4; ++r) { m_r[r] = -1e30f; l_r[r] = 0.f; }
    const float* kb = K + (size_t)(b * H + h) * 1024 * D;
    const float* vb = V + (size_t)(b * H + h) * 1024 * D;
    for (int tb = 0; tb < 16; ++tb) {
        if (!flags[tb]) continue;
        __syncthreads();
        stage_rm_fb(kb + tb * 64 * D, kq_hi, kq_lo, 1.0f);
        stage_tr_fb(vb + tb * 64 * D, vt_hi, vt_lo);
        __syncthreads();
        f32x4 s[4];
#pragma unroll
        for (int j = 0; j < 4; ++j) {
            s[j] = f32x4{0.f, 0.f, 0.f, 0.f};
#pragma unroll
            for (int kk = 0; kk < 2; ++kk) {
                bf16x8 bhf = ld_fragb(kq_hi, j * 16 + l16, kk * 32 + g * 8);
                bf16x8 blf = ld_fragb(kq_lo, j * 16 + l16, kk * 32 + g * 8);
                s[j] = MFMABF(qh[kk], bhf, s[j]);
                s[j] = MFMABF(qh[kk], blf, s[j]);
                s[j] = MFMABF(ql[kk], bhf, s[j]);
            }
        }
        float rmax[4];
#pragma unroll
        for (int r = 0; r < 4; ++r)
            rmax[r] = fmaxf(fmaxf(s[0][r], s[1][r]), fmaxf(s[2][r], s[3][r]));
#pragma unroll
        for (int off = 1; off < 16; off <<= 1)
#pragma unroll
            for (int r = 0; r < 4; ++r)
                rmax[r] = fmaxf(rmax[r], __shfl_xor(rmax[r], off, 64));
        float alpha[4], psum[4];
#pragma unroll
        for (int r = 0; r < 4; ++r) {
            float mn = fmaxf(m_r[r], rmax[r]);
            alpha[r] = __expf(m_r[r] - mn);
            m_r[r]   = mn;
            psum[r]  = 0.f;
        }
#pragma unroll
        for (int j = 0; j < 4; ++j)
#pragma unroll
            for (int r = 0; r < 4; ++r) {
                float pe = __expf(s[j][r] - m_r[r]);
                s[j][r] = pe;
                psum[r] += pe;
            }
#pragma unroll
        for (int off = 1; off < 16; off <<= 1)
#pragma unroll
            for (int r = 0; r < 4; ++r)
                psum[r] += __shfl_xor(psum[r], off, 64);
#pragma unroll
        for (int r = 0; r < 4; ++r)
            l_r[r] = l_r[r] * alpha[r] + psum[r];
#pragma unroll
        for (int j = 0; j < 4; ++j)
#pragma unroll
            for (int r = 0; r < 4; ++r)
                acc[j][r] *= alpha[r];
#pragma unroll
        for (int j = 0; j < 4; ++j)
#pragma unroll
            for (int r = 0; r < 4; ++r) {
                int row = w * 16 + g * 4 + r;
                *(unsigned short*)(p_smf + swz_off(row, j * 16 + l16)) = f2bf(s[j][r]);
            }
        __syncthreads();
#pragma unroll
        for (int kk = 0; kk < 2; ++kk) {
            bf16x8 pa = ld_fragb(p_smf, w * 16 + l16, kk * 32 + g * 8);
#pragma unroll
            for (int jd = 0; jd < 4; ++jd) {
                bf16x8 vh = ld_fragb(vt_hi, jd * 16 + l16, kk * 32 + g * 8);
                bf16x8 vl = ld_fragb(vt_lo, jd * 16 + l16, kk * 32 + g * 8);
                acc[jd] = MFMABF(pa, vh, acc[jd]);
                acc[jd] = MFMABF(pa, vl, acc[jd]);
            }
        }
    }
#pragma unroll
    for (int r = 0; r < 4; ++r) {
        float inv = 1.0f / l_r[r];
        int f = fb * 64 + w * 16 + g * 4 + r;
        float* ob = Out + ((size_t)(b * F + f) * H + h) * D;
#pragma unroll
        for (int jd = 0; jd < 4; ++jd)
            ob[jd * 16 + l16] = acc[jd][r] * inv;
    }
}

extern "C" void kernel_launch(void* const* d_in, const int* in_sizes, int n_in,
                              void* d_out, int out_size, void* d_ws, size_t ws_size,
                              hipStream_t stream) {
    const float* q = (const float*)d_in[0];
    const float* k = (const float*)d_in[1];
    const float* v = (const float*)d_in[2];
    const float* m = (const float*)d_in[3];
    float* out = (float*)d_out;
    if (ws_size >= WS_NEED) {
        bigbird_prepass<<<dim3(512), dim3(256), 0, stream>>>(k, v, (char*)d_ws);
        bigbird_main<<<dim3(512), dim3(256), 0, stream>>>(q, m, (const char*)d_ws, out);
    } else {
        bigbird_kernel_fb<<<dim3(512), dim3(256), 0, stream>>>(q, k, v, m, out);
    }
}